// Round 1
// baseline (4497.298 us; speedup 1.0000x reference)
//
#include <hip/hip_runtime.h>

// GRU decoder: B=256, I=512, H=1024, S=128, heads 512->128->3 and 512->128->6.
// Strategy: fp16 MFMA (16x16x32) with fp32 accumulate; 128 x {gates, outproj}
// dependent dispatches + prep + heads, all graph-captured.

#define HID 1024
#define INP 512
#define BATCH 256
#define SEQ 128

typedef _Float16 f16x8 __attribute__((ext_vector_type(8)));
typedef float f32x4 __attribute__((ext_vector_type(4)));

__device__ __forceinline__ float fast_sigmoid(float x) {
    return 1.0f / (1.0f + __expf(-x));
}
__device__ __forceinline__ float fast_tanh(float x) {
    return 1.0f - 2.0f / (__expf(2.0f * x) + 1.0f);
}

// ---- prep: convert weights fp32 -> fp16, init h0 (fp32 + fp16) ----
__global__ void prep_kernel(const float* __restrict__ Wih, const float* __restrict__ Whh,
                            const float* __restrict__ Wout, const float* __restrict__ Wm1,
                            const float* __restrict__ Wc1, const float* __restrict__ ehid,
                            _Float16* __restrict__ WihH, _Float16* __restrict__ WhhH,
                            _Float16* __restrict__ WoutH, _Float16* __restrict__ Wm1H,
                            _Float16* __restrict__ Wc1H,
                            float* __restrict__ h32, _Float16* __restrict__ h16) {
    const size_t N0 = (size_t)3*HID*INP;          // 1572864
    const size_t N1 = N0 + (size_t)3*HID*HID;     // 4718592
    const size_t N2 = N1 + (size_t)INP*HID;       // 5242880
    const size_t N3 = N2 + (size_t)128*INP;       // 5308416
    const size_t N4 = N3 + (size_t)128*INP;       // 5373952
    const size_t N5 = N4 + (size_t)BATCH*HID;     // 5636096
    size_t stride = (size_t)gridDim.x * blockDim.x;
    for (size_t i = (size_t)blockIdx.x * blockDim.x + threadIdx.x; i < N5; i += stride) {
        if (i < N0) WihH[i] = (_Float16)Wih[i];
        else if (i < N1) WhhH[i - N0] = (_Float16)Whh[i - N0];
        else if (i < N2) WoutH[i - N1] = (_Float16)Wout[i - N1];
        else if (i < N3) Wm1H[i - N2] = (_Float16)Wm1[i - N2];
        else if (i < N4) Wc1H[i - N3] = (_Float16)Wc1[i - N3];
        else { size_t j = i - N4; float v = ehid[j]; h32[j] = v; h16[j] = (_Float16)v; }
    }
}

// ---- gates: h' = GRU(relu(x), h).  grid 256 WGs: 4 b-tiles(64 rows) x 64 j-tiles(16 cols),
// XCD-swizzled so each XCD owns a contiguous 128-col weight slice (L2-resident). ----
__global__ __launch_bounds__(256) void gates_kernel(
    const _Float16* __restrict__ WihH, const _Float16* __restrict__ WhhH,
    const float* __restrict__ bih, const float* __restrict__ bhh,
    const _Float16* __restrict__ outs,
    const float* __restrict__ h32p, const _Float16* __restrict__ h16p,
    float* __restrict__ h32n, _Float16* __restrict__ h16n,
    int t)
{
    int w = blockIdx.x;
    int xcd = w & 7;
    int s = w >> 3;
    int jj = xcd * 8 + (s >> 2);     // 0..63 -> 16 h-cols each
    int b4 = s & 3;                  // 0..3  -> 64 rows each
    int wave = threadIdx.x >> 6;
    int lane = threadIdx.x & 63;
    int l15 = lane & 15;
    int koff = (lane >> 4) * 8;
    int row = b4 * 64 + wave * 16 + l15;   // A-operand row
    int jcol = jj * 16;

    f32x4 ar = {0.f,0.f,0.f,0.f}, az = {0.f,0.f,0.f,0.f};
    f32x4 ai = {0.f,0.f,0.f,0.f}, ah = {0.f,0.f,0.f,0.f};

    // W_ih rows: r at jcol, z at H+jcol, n at 2H+jcol
    const _Float16* wr = WihH + (size_t)(jcol + l15) * INP + koff;
    const _Float16* wz = wr + (size_t)HID * INP;
    const _Float16* wn = wz + (size_t)HID * INP;
    if (t > 0) {
        const _Float16* xp = outs + ((size_t)row * SEQ + (t - 1)) * INP + koff;
        #pragma unroll 4
        for (int kk = 0; kk < INP; kk += 32) {
            f16x8 a = *(const f16x8*)(xp + kk);
            #pragma unroll
            for (int q = 0; q < 8; ++q) a[q] = a[q] > (_Float16)0.f ? a[q] : (_Float16)0.f;
            f16x8 br = *(const f16x8*)(wr + kk);
            f16x8 bz = *(const f16x8*)(wz + kk);
            f16x8 bn = *(const f16x8*)(wn + kk);
            ar = __builtin_amdgcn_mfma_f32_16x16x32_f16(a, br, ar, 0, 0, 0);
            az = __builtin_amdgcn_mfma_f32_16x16x32_f16(a, bz, az, 0, 0, 0);
            ai = __builtin_amdgcn_mfma_f32_16x16x32_f16(a, bn, ai, 0, 0, 0);
        }
    }
    const _Float16* hr = WhhH + (size_t)(jcol + l15) * HID + koff;
    const _Float16* hz = hr + (size_t)HID * HID;
    const _Float16* hn = hz + (size_t)HID * HID;
    const _Float16* hp = h16p + (size_t)row * HID + koff;
    #pragma unroll 4
    for (int kk = 0; kk < HID; kk += 32) {
        f16x8 a = *(const f16x8*)(hp + kk);
        f16x8 br = *(const f16x8*)(hr + kk);
        f16x8 bz = *(const f16x8*)(hz + kk);
        f16x8 bn = *(const f16x8*)(hn + kk);
        ar = __builtin_amdgcn_mfma_f32_16x16x32_f16(a, br, ar, 0, 0, 0);
        az = __builtin_amdgcn_mfma_f32_16x16x32_f16(a, bz, az, 0, 0, 0);
        ah = __builtin_amdgcn_mfma_f32_16x16x32_f16(a, bn, ah, 0, 0, 0);
    }
    // epilogue: C/D layout col = lane&15 (gate col), row = (lane>>4)*4 + i
    int jc = jcol + l15;
    float brr = bih[jc] + bhh[jc];
    float bzz = bih[HID + jc] + bhh[HID + jc];
    float bin = bih[2 * HID + jc];
    float bhn = bhh[2 * HID + jc];
    int crow0 = b4 * 64 + wave * 16 + (lane >> 4) * 4;
    #pragma unroll
    for (int i = 0; i < 4; ++i) {
        int r = crow0 + i;
        float rr = fast_sigmoid(ar[i] + brr);
        float zz = fast_sigmoid(az[i] + bzz);
        float nn = fast_tanh(ai[i] + bin + rr * (ah[i] + bhn));
        float hold = h32p[(size_t)r * HID + jc];
        float hv = (1.0f - zz) * nn + zz * hold;
        h32n[(size_t)r * HID + jc] = hv;
        h16n[(size_t)r * HID + jc] = (_Float16)hv;
    }
}

// ---- out projection: out_t = h' @ W_out^T + b_out  -> outs[b][t][:] (fp16) ----
__global__ __launch_bounds__(256) void outproj_kernel(
    const _Float16* __restrict__ WoutH, const float* __restrict__ bout,
    const _Float16* __restrict__ h16n, _Float16* __restrict__ outs, int t)
{
    int w = blockIdx.x;          // 128 WGs: 8 b-tiles(32) x 16 c-tiles(32)
    int b8 = w >> 4;
    int c16 = w & 15;
    int wave = threadIdx.x >> 6;
    int lane = threadIdx.x & 63;
    int l15 = lane & 15;
    int koff = (lane >> 4) * 8;
    int row = b8 * 32 + (wave & 1) * 16 + l15;
    int cbase = c16 * 32 + (wave >> 1) * 16;
    f32x4 acc = {0.f,0.f,0.f,0.f};
    const _Float16* ap = h16n + (size_t)row * HID + koff;
    const _Float16* bp = WoutH + (size_t)(cbase + l15) * HID + koff;
    #pragma unroll 4
    for (int kk = 0; kk < HID; kk += 32) {
        f16x8 a = *(const f16x8*)(ap + kk);
        f16x8 b = *(const f16x8*)(bp + kk);
        acc = __builtin_amdgcn_mfma_f32_16x16x32_f16(a, b, acc, 0, 0, 0);
    }
    int c = cbase + l15;
    float bb = bout[c];
    int crow0 = b8 * 32 + (wave & 1) * 16 + (lane >> 4) * 4;
    #pragma unroll
    for (int i = 0; i < 4; ++i) {
        int r = crow0 + i;
        outs[((size_t)r * SEQ + t) * INP + c] = (_Float16)(acc[i] + bb);
    }
}

// ---- heads: means = relu(outs@Wm1^T+bm1)@Wm2^T+bm2 ; covs likewise ----
__global__ __launch_bounds__(256) void heads_kernel(
    const _Float16* __restrict__ outs,
    const _Float16* __restrict__ Wm1H, const float* __restrict__ bm1,
    const float* __restrict__ Wm2, const float* __restrict__ bm2,
    const _Float16* __restrict__ Wc1H, const float* __restrict__ bc1,
    const float* __restrict__ Wc2, const float* __restrict__ bc2,
    float* __restrict__ dout)
{
    __shared__ _Float16 hid[128][136];
    int b = blockIdx.x;                 // one batch element = 128 rows of outs
    int wave = threadIdx.x >> 6;
    int lane = threadIdx.x & 63;
    int l15 = lane & 15;
    int koff = (lane >> 4) * 8;
    const size_t rowbase = (size_t)b * 128;
    for (int head = 0; head < 2; ++head) {
        const _Float16* W1 = head ? Wc1H : Wm1H;
        const float* b1 = head ? bc1 : bm1;
        f32x4 acc[2][8];
        #pragma unroll
        for (int rf = 0; rf < 2; ++rf)
            #pragma unroll
            for (int ct = 0; ct < 8; ++ct) acc[rf][ct] = (f32x4){0.f,0.f,0.f,0.f};
        for (int kk = 0; kk < INP; kk += 32) {
            f16x8 a0 = *(const f16x8*)(outs + (rowbase + wave * 32 + l15) * INP + kk + koff);
            f16x8 a1 = *(const f16x8*)(outs + (rowbase + wave * 32 + 16 + l15) * INP + kk + koff);
            #pragma unroll
            for (int ct = 0; ct < 8; ++ct) {
                f16x8 bb = *(const f16x8*)(W1 + (size_t)(ct * 16 + l15) * INP + kk + koff);
                acc[0][ct] = __builtin_amdgcn_mfma_f32_16x16x32_f16(a0, bb, acc[0][ct], 0, 0, 0);
                acc[1][ct] = __builtin_amdgcn_mfma_f32_16x16x32_f16(a1, bb, acc[1][ct], 0, 0, 0);
            }
        }
        #pragma unroll
        for (int rf = 0; rf < 2; ++rf) {
            int rl = wave * 32 + rf * 16 + (lane >> 4) * 4;
            #pragma unroll
            for (int ct = 0; ct < 8; ++ct) {
                int col = ct * 16 + l15;
                float bb1 = b1[col];
                #pragma unroll
                for (int i = 0; i < 4; ++i) {
                    float v = acc[rf][ct][i] + bb1;
                    hid[rl + i][col] = (_Float16)(v > 0.f ? v : 0.f);
                }
            }
        }
        __syncthreads();
        if (threadIdx.x < 128) {
            int srow = threadIdx.x;
            if (head == 0) {
                float a0 = bm2[0], a1 = bm2[1], a2 = bm2[2];
                for (int k = 0; k < 128; ++k) {
                    float hv = (float)hid[srow][k];
                    a0 += hv * Wm2[k];
                    a1 += hv * Wm2[128 + k];
                    a2 += hv * Wm2[256 + k];
                }
                size_t o = ((size_t)b * 128 + srow) * 3;
                dout[o] = a0; dout[o + 1] = a1; dout[o + 2] = a2;
            } else {
                float a[6];
                #pragma unroll
                for (int m = 0; m < 6; ++m) a[m] = bc2[m];
                for (int k = 0; k < 128; ++k) {
                    float hv = (float)hid[srow][k];
                    #pragma unroll
                    for (int m = 0; m < 6; ++m) a[m] += hv * Wc2[m * 128 + k];
                }
                size_t o = (size_t)BATCH * SEQ * 3 + ((size_t)b * 128 + srow) * 6;
                #pragma unroll
                for (int m = 0; m < 6; ++m) dout[o + m] = a[m];
            }
        }
        __syncthreads();
    }
}

extern "C" void kernel_launch(void* const* d_in, const int* in_sizes, int n_in,
                              void* d_out, int out_size, void* d_ws, size_t ws_size,
                              hipStream_t stream) {
    (void)in_sizes; (void)n_in; (void)out_size; (void)ws_size;
    const float* ehid = (const float*)d_in[1];   // encoder_hidden [1,B,H]
    const float* Wih  = (const float*)d_in[2];
    const float* Whh  = (const float*)d_in[3];
    const float* bih  = (const float*)d_in[4];
    const float* bhh  = (const float*)d_in[5];
    const float* Wout = (const float*)d_in[6];
    const float* bout = (const float*)d_in[7];
    const float* Wm1  = (const float*)d_in[8];
    const float* bm1  = (const float*)d_in[9];
    const float* Wm2  = (const float*)d_in[10];
    const float* bm2  = (const float*)d_in[11];
    const float* Wc1  = (const float*)d_in[12];
    const float* bc1  = (const float*)d_in[13];
    const float* Wc2  = (const float*)d_in[14];
    const float* bc2  = (const float*)d_in[15];
    float* dout = (float*)d_out;

    char* ws = (char*)d_ws;
    _Float16* WihH  = (_Float16*)(ws);                 // 3,145,728 B
    _Float16* WhhH  = (_Float16*)(ws + 3145728);       // 6,291,456 B
    _Float16* WoutH = (_Float16*)(ws + 9437184);       // 1,048,576 B
    _Float16* Wm1H  = (_Float16*)(ws + 10485760);      //   131,072 B
    _Float16* Wc1H  = (_Float16*)(ws + 10616832);      //   131,072 B
    float*    h32   = (float*)   (ws + 10747904);      // 2 x 1,048,576 B
    _Float16* h16   = (_Float16*)(ws + 12845056);      // 2 x   524,288 B
    _Float16* outs  = (_Float16*)(ws + 13893632);      // 33,554,432 B
    // total ~47.5 MB of d_ws

    prep_kernel<<<2048, 256, 0, stream>>>(Wih, Whh, Wout, Wm1, Wc1, ehid,
                                          WihH, WhhH, WoutH, Wm1H, Wc1H, h32, h16);
    for (int t = 0; t < SEQ; ++t) {
        int cur = t & 1, nxt = (t + 1) & 1;
        gates_kernel<<<256, 256, 0, stream>>>(WihH, WhhH, bih, bhh, outs,
                                              h32 + (size_t)cur * BATCH * HID,
                                              h16 + (size_t)cur * BATCH * HID,
                                              h32 + (size_t)nxt * BATCH * HID,
                                              h16 + (size_t)nxt * BATCH * HID, t);
        outproj_kernel<<<128, 256, 0, stream>>>(WoutH, bout,
                                                h16 + (size_t)nxt * BATCH * HID, outs, t);
    }
    heads_kernel<<<256, 256, 0, stream>>>(outs, Wm1H, bm1, Wm2, bm2,
                                          Wc1H, bc1, Wc2, bc2, dout);
}